// Round 5
// baseline (59.378 us; speedup 1.0000x reference)
//
#include <hip/hip_runtime.h>
#include <math.h>

#define TILE_SZ 16
#define NEARP 0.8f
#define FARP 1000.0f
#define ATHR (1.0f/255.0f)
#define TTHR 0.0001f

// Record layout (16 floats, 64B), float4-aligned groups:
//  [0]=u    [1]=v     [2]=conic_a [3]=conic_b
//  [4]=conic_c [5]=alpha [6]=z    [7]=color_r
//  [8]=color_g [9]=color_b [10]=pad [11]=pad
//  [12]=t0x [13]=t1x  [14]=t0y    [15]=t1y     <- bounds as one float4

__global__ void preprocess_kernel(const float* __restrict__ pc,
                                  const float* __restrict__ feat,
                                  const int* __restrict__ invalid_mask,
                                  const float* __restrict__ K,
                                  const float* __restrict__ qcam,
                                  const float* __restrict__ tcam,
                                  const int* __restrict__ cam_h,
                                  const int* __restrict__ cam_w,
                                  const int* __restrict__ sh_band,
                                  float* __restrict__ recs,
                                  float* __restrict__ keys,
                                  int N)
{
    int i = blockIdx.x * blockDim.x + threadIdx.x;
    if (i >= N) return;

    float fx = K[0], cx = K[2], fy = K[4], cy = K[5];
    int H = cam_h[0], W = cam_w[0];

    float qx = qcam[0], qy = qcam[1], qz = qcam[2], qw = qcam[3];
    float qn = sqrtf(qx*qx + qy*qy + qz*qz + qw*qw);
    qx /= qn; qy /= qn; qz /= qn; qw /= qn;
    float R00 = 1.f-2.f*(qy*qy+qz*qz), R01 = 2.f*(qx*qy-qw*qz), R02 = 2.f*(qx*qz+qw*qy);
    float R10 = 2.f*(qx*qy+qw*qz), R11 = 1.f-2.f*(qx*qx+qz*qz), R12 = 2.f*(qy*qz-qw*qx);
    float R20 = 2.f*(qx*qz-qw*qy), R21 = 2.f*(qy*qz+qw*qx), R22 = 1.f-2.f*(qx*qx+qy*qy);
    float C00 = R00, C01 = R10, C02 = R20;
    float C10 = R01, C11 = R11, C12 = R21;
    float C20 = R02, C21 = R12, C22 = R22;
    float tx = tcam[0], ty = tcam[1], tz = tcam[2];
    float tcx = -(C00*tx + C01*ty + C02*tz);
    float tcy = -(C10*tx + C11*ty + C12*tz);
    float tcz = -(C20*tx + C21*ty + C22*tz);

    float px = pc[i*3+0], py = pc[i*3+1], pz = pc[i*3+2];
    float xc = C00*px + C01*py + C02*pz + tcx;
    float yc = C10*px + C11*py + C12*pz + tcy;
    float zc = C20*px + C21*py + C22*pz + tcz;
    float inv_z = 1.0f / zc;
    float u = fx * xc * inv_z + cx;
    float v = fy * yc * inv_z + cy;

    bool valid = (invalid_mask[i] == 0) && (zc > NEARP) && (zc < FARP)
              && (u > -4.0f*TILE_SZ) && (u < (float)W + 4.0f*TILE_SZ)
              && (v > -4.0f*TILE_SZ) && (v < (float)H + 4.0f*TILE_SZ);

    float q0 = feat[i*56+0], q1 = feat[i*56+1], q2 = feat[i*56+2], q3 = feat[i*56+3];
    float pn = sqrtf(q0*q0 + q1*q1 + q2*q2 + q3*q3);
    q0 /= pn; q1 /= pn; q2 /= pn; q3 /= pn;
    float P00 = 1.f-2.f*(q1*q1+q2*q2), P01 = 2.f*(q0*q1-q3*q2), P02 = 2.f*(q0*q2+q3*q1);
    float P10 = 2.f*(q0*q1+q3*q2), P11 = 1.f-2.f*(q0*q0+q2*q2), P12 = 2.f*(q1*q2-q3*q0);
    float P20 = 2.f*(q0*q2-q3*q1), P21 = 2.f*(q1*q2+q3*q0), P22 = 1.f-2.f*(q0*q0+q1*q1);
    float s0 = expf(feat[i*56+4]), s1 = expf(feat[i*56+5]), s2 = expf(feat[i*56+6]);
    float M00 = P00*s0, M01 = P01*s1, M02 = P02*s2;
    float M10 = P10*s0, M11 = P11*s1, M12 = P12*s2;
    float M20 = P20*s0, M21 = P21*s1, M22 = P22*s2;
    float S00 = M00*M00 + M01*M01 + M02*M02;
    float S01 = M00*M10 + M01*M11 + M02*M12;
    float S02 = M00*M20 + M01*M21 + M02*M22;
    float S11 = M10*M10 + M11*M11 + M12*M12;
    float S12 = M10*M20 + M11*M21 + M12*M22;
    float S22 = M20*M20 + M21*M21 + M22*M22;
    float T00 = C00*S00 + C01*S01 + C02*S02;
    float T01 = C00*S01 + C01*S11 + C02*S12;
    float T02 = C00*S02 + C01*S12 + C02*S22;
    float T10 = C10*S00 + C11*S01 + C12*S02;
    float T11 = C10*S01 + C11*S11 + C12*S12;
    float T12 = C10*S02 + C11*S12 + C12*S22;
    float T20 = C20*S00 + C21*S01 + C22*S02;
    float T21 = C20*S01 + C21*S11 + C22*S12;
    float T22 = C20*S02 + C21*S12 + C22*S22;
    float G00 = T00*C00 + T01*C01 + T02*C02;
    float G01 = T00*C10 + T01*C11 + T02*C12;
    float G02 = T00*C20 + T01*C21 + T02*C22;
    float G11 = T10*C10 + T11*C11 + T12*C12;
    float G12 = T10*C20 + T11*C21 + T12*C22;
    float G22 = T20*C20 + T21*C21 + T22*C22;
    float j00 = fx * inv_z;
    float j02 = -fx * xc * inv_z * inv_z;
    float j11 = fy * inv_z;
    float j12 = -fy * yc * inv_z * inv_z;
    float a0 = j00*G00 + j02*G02;
    float a1 = j00*G01 + j02*G12;
    float a2 = j00*G02 + j02*G22;
    float b1 = j11*G11 + j12*G12;
    float b2 = j11*G12 + j12*G22;
    float cov00 = a0*j00 + a2*j02;
    float cov01 = a1*j11 + a2*j12;
    float cov11 = b1*j11 + b2*j12;

    float A = cov00 + 0.3f;
    float B = cov01;
    float Cc = cov11 + 0.3f;
    float det = fmaxf(A*Cc - B*B, 1e-9f);
    float conic_a = Cc / det;
    float conic_b = -B / det;
    float conic_c = A / det;
    float mid = 0.5f * (A + Cc);
    float lam = mid + sqrtf(fmaxf(mid*mid - det, 1e-9f));
    float radii = ceilf(3.0f * sqrtf(lam));

    float aval = feat[i*56+7];
    float alpha = 1.0f / (1.0f + expf(-aval));

    float dnx = px - tx, dny = py - ty, dnz = pz - tz;
    float dn = sqrtf(dnx*dnx + dny*dny + dnz*dnz);
    float dx = dnx/dn, dy = dny/dn, dz = dnz/dn;
    float xx = dx*dx, yy = dy*dy, zz = dz*dz;
    float xy = dx*dy, yz = dy*dz, xz = dx*dz;
    float basis[16];
    basis[0] = 0.28209479177387814f;
    basis[1] = -0.4886025119029199f * dy;
    basis[2] = 0.4886025119029199f * dz;
    basis[3] = -0.4886025119029199f * dx;
    basis[4] = 1.0925484305920792f * xy;
    basis[5] = -1.0925484305920792f * yz;
    basis[6] = 0.31539156525252005f * (2.f*zz - xx - yy);
    basis[7] = -1.0925484305920792f * xz;
    basis[8] = 0.5462742152960396f * (xx - yy);
    basis[9] = -0.5900435899266435f * dy * (3.f*xx - yy);
    basis[10] = 2.890611442640554f * xy * dz;
    basis[11] = -0.4570457994644658f * dy * (4.f*zz - xx - yy);
    basis[12] = 0.3731763325901154f * dz * (2.f*zz - 3.f*xx - 3.f*yy);
    basis[13] = -0.4570457994644658f * dx * (4.f*zz - xx - yy);
    basis[14] = 1.445305721320277f * dz * (xx - yy);
    basis[15] = -0.5900435899266435f * dx * (xx - 3.f*yy);
    int band = sh_band[0];
    int kc = (band + 1) * (band + 1);
    float c0 = 0.f, c1 = 0.f, c2 = 0.f;
#pragma unroll
    for (int j = 0; j < 16; j++) {
        if (j < kc) {
            c0 += basis[j] * feat[i*56 + 8 + 0*16 + j];
            c1 += basis[j] * feat[i*56 + 8 + 1*16 + j];
            c2 += basis[j] * feat[i*56 + 8 + 2*16 + j];
        }
    }
    c0 = fmaxf(c0 + 0.5f, 0.0f);
    c1 = fmaxf(c1 + 0.5f, 0.0f);
    c2 = fmaxf(c2 + 0.5f, 0.0f);

    float tiles_x = (float)(W / TILE_SZ);
    float tiles_y = (float)(H / TILE_SZ);
    float t0x = fminf(fmaxf(floorf((u - radii) / TILE_SZ), 0.0f), tiles_x - 1.0f);
    float t1x = fminf(fmaxf(floorf((u + radii) / TILE_SZ), 0.0f), tiles_x - 1.0f);
    float t0y = fminf(fmaxf(floorf((v - radii) / TILE_SZ), 0.0f), tiles_y - 1.0f);
    float t1y = fminf(fmaxf(floorf((v + radii) / TILE_SZ), 0.0f), tiles_y - 1.0f);

    if (!valid) {
        t0x = 1e30f; t1x = -1e30f; t0y = 1e30f; t1y = -1e30f;
        alpha = 0.0f;
    }

    float* r = recs + (size_t)i * 16;
    r[0] = u;  r[1] = v;  r[2] = conic_a; r[3] = conic_b;
    r[4] = conic_c; r[5] = alpha; r[6] = zc; r[7] = c0;
    r[8] = c1; r[9] = c2; r[10] = 0.f; r[11] = 0.f;
    r[12] = t0x; r[13] = t1x; r[14] = t0y; r[15] = t1y;

    keys[i] = valid ? zc : INFINITY;
}

// 2D-parallel stable rank: block (ic,jc) compares 256 i's vs 256 LDS j-keys.
// Vectorized float4 LDS scan (16 keys in flight with unroll 4).
__global__ void rank_kernel(const float* __restrict__ keys,
                            int* __restrict__ partial,
                            int N)
{
    __shared__ float sk[256];
    int ic = blockIdx.x, jc = blockIdx.y;
    int tid = threadIdx.x;
    int i = ic * 256 + tid;
    int jbase = jc * 256;
    int m = min(256, N - jbase);
    if (tid < m) sk[tid] = keys[jbase + tid];
    __syncthreads();
    if (i >= N) return;
    float ki = keys[i];
    int r = 0;
    int m4 = m & ~3;
#pragma unroll 4
    for (int j = 0; j < m4; j += 4) {
        float4 k4 = *(const float4*)(sk + j);
        r += (k4.x < ki) || (k4.x == ki && (jbase + j    ) < i);
        r += (k4.y < ki) || (k4.y == ki && (jbase + j + 1) < i);
        r += (k4.z < ki) || (k4.z == ki && (jbase + j + 2) < i);
        r += (k4.w < ki) || (k4.w == ki && (jbase + j + 3) < i);
    }
    for (int j = m4; j < m; j++) {
        float kj = sk[j];
        r += (kj < ki) || (kj == ki && (jbase + j) < i);
    }
    partial[jc * N + i] = r;
}

__global__ void scatter_kernel(const int* __restrict__ partial,
                               const float* __restrict__ recs,
                               float* __restrict__ sorted_recs,
                               int N, int nchunks)
{
    int i = blockIdx.x * blockDim.x + threadIdx.x;
    if (i >= N) return;
    int rank = 0;
    for (int c = 0; c < nchunks; c++) rank += partial[c * N + i];
    const float4* src = (const float4*)(recs + (size_t)i * 16);
    float4* dst = (float4*)(sorted_recs + (size_t)rank * 16);
    dst[0] = src[0]; dst[1] = src[1]; dst[2] = src[2]; dst[3] = src[3];
}

// Fused per-tile raster: one block (256 threads = 4 waves) per 16x16 tile.
// Membership once per tile; 2-barrier compaction; double-buffered staging;
// composite uses a 3-deep rotating register pipeline so LDS latency (~120cy)
// hides under ~2 records of VALU work.
#define LIST_CAP 2048

#define COMPOSITE(P0,P1,P2) do { \
    float du = pxf - P0.x; \
    float dv = pyf - P0.y; \
    float power = -0.5f * (P0.z*du*du + P1.x*dv*dv) - P0.w*du*dv; \
    float ai = fminf(P1.y * expf(fminf(power, 0.0f)), 0.99f); \
    bool eff = (ai >= ATHR) && (T > TTHR); \
    float w = eff ? T * ai : 0.0f; \
    cr  += w * P1.w; \
    cg  += w * P2.x; \
    cbl += w * P2.y; \
    dep += w * P1.z; \
    acc += w; \
    cnt_px += eff; \
    T = eff ? T * (1.0f - ai) : T; \
} while (0)

#define LDREC(V0,V1,V2,IDX) do { \
    const float* _q = spb + (IDX) * 16; \
    V0 = *(const float4*)_q; \
    V1 = *(const float4*)(_q + 4); \
    V2 = *(const float4*)(_q + 8); \
} while (0)

__global__ __launch_bounds__(256) void raster_kernel(
        const float* __restrict__ sorted_recs, int N,
        const int* __restrict__ cam_h,
        const int* __restrict__ cam_w,
        float* __restrict__ out)
{
    int W = cam_w[0], H = cam_h[0];
    int tiles_x = W / TILE_SZ;
    int bx = blockIdx.x % tiles_x;
    int by = blockIdx.x / tiles_x;
    int tid = threadIdx.x;
    int lane = tid & 63;
    int wv = tid >> 6;
    int px = bx * TILE_SZ + (wv & 1) * 8 + (lane & 7);
    int py = by * TILE_SZ + (wv >> 1) * 8 + (lane >> 3);
    float pxf = (float)px + 0.5f;
    float pyf = (float)py + 0.5f;
    float txf = (float)bx;
    float tyf = (float)by;

    float T = 1.0f;
    float cr = 0.f, cg = 0.f, cbl = 0.f;
    float dep = 0.f, acc = 0.f;
    int cnt_px = 0;

    __shared__ unsigned short list[LIST_CAP];   // 4KB
    __shared__ float sp[2][64 * 16];            // 8KB double-buffered staging
    __shared__ int cntmat[32];                  // (round, wave) member counts

    bool alldead = false;

    for (int seg = 0; seg < N && !alldead; seg += LIST_CAP) {
        int segN = min(LIST_CAP, N - seg);
        int rounds = (segN + 255) >> 8;         // <= 8

        // ---- Phase A: batched bound loads (independent, pipelined) ----
        float4 bnd[8];
#pragma unroll
        for (int r = 0; r < 8; r++) {
            int local = (r << 8) + tid;
            if (r < rounds && local < segN) {
                bnd[r] = *(const float4*)(sorted_recs + (size_t)(seg + local) * 16 + 12);
            } else {
                bnd[r].x = 1e30f; bnd[r].y = -1e30f; bnd[r].z = 1e30f; bnd[r].w = -1e30f;
            }
        }
        unsigned pmask = 0;
#pragma unroll
        for (int r = 0; r < 8; r++) {
            bool pred = (txf >= bnd[r].x) && (txf <= bnd[r].y)
                     && (tyf >= bnd[r].z) && (tyf <= bnd[r].w);
            pmask |= ((unsigned)pred) << r;
        }
#pragma unroll
        for (int r = 0; r < 8; r++) {
            unsigned long long m = __ballot((pmask >> r) & 1u);
            if (lane == 0) cntmat[r * 4 + wv] = __popcll(m);
        }
        __syncthreads();

        // ---- Phase B: register prefix over 32 cells, then compacted writes ----
        int base[8];
        int total = 0;
#pragma unroll
        for (int k = 0; k < 32; k++) {
            if ((k & 3) == wv) base[k >> 2] = total;
            total += cntmat[k];
        }
        int cnt = total;
#pragma unroll
        for (int r = 0; r < 8; r++) {
            bool pred = (pmask >> r) & 1u;
            unsigned long long m = __ballot(pred);
            if (pred) {
                int below = __popcll(m & ((1ull << lane) - 1ull));
                list[base[r] + below] = (unsigned short)((r << 8) + tid);
            }
        }
        __syncthreads();

        // ---- Phase C: double-buffered chunked composite ----
        {
            int m0 = min(64, cnt);
            if (tid < m0 * 4) {
                int gi = seg + (int)list[tid >> 2];
                *(float4*)&sp[0][(tid >> 2) * 16 + (tid & 3) * 4] =
                    ((const float4*)(sorted_recs + (size_t)gi * 16))[tid & 3];
            }
        }
        __syncthreads();

        int buf = 0;
        for (int c = 0; c < cnt && !alldead; c += 64) {
            int m2 = min(64, cnt - c);
            int mn = min(64, cnt - (c + 64));

            // issue next-chunk global loads early (hide under composite)
            float4 nxt; bool have = false;
            if (mn > 0 && tid < mn * 4) {
                int gi = seg + (int)list[c + 64 + (tid >> 2)];
                nxt = ((const float4*)(sorted_recs + (size_t)gi * 16))[tid & 3];
                have = true;
            }

            // composite current chunk: 3-deep rotating register pipeline
            if (!__all(T <= TTHR)) {
                const float* spb = sp[buf];
                float4 A0, A1, A2, B0, B1, B2, C0, C1, C2;
                if (m2 > 0) LDREC(A0, A1, A2, 0);
                if (m2 > 1) LDREC(B0, B1, B2, 1);
                for (int j = 0; j < m2; j += 3) {
                    if (j + 2 < m2) LDREC(C0, C1, C2, j + 2);
                    COMPOSITE(A0, A1, A2);
                    if (j + 1 >= m2) break;
                    if (j + 3 < m2) LDREC(A0, A1, A2, j + 3);
                    COMPOSITE(B0, B1, B2);
                    if (j + 2 >= m2) break;
                    if (j + 4 < m2) LDREC(B0, B1, B2, j + 4);
                    COMPOSITE(C0, C1, C2);
                }
            }

            alldead = (bool)__syncthreads_and((T <= TTHR) ? 1 : 0);
            if (alldead) break;

            if (have) {
                *(float4*)&sp[buf ^ 1][(tid >> 2) * 16 + (tid & 3) * 4] = nxt;
            }
            __syncthreads();
            buf ^= 1;
        }
    }

    int pix = py * W + px;
    int HW = H * W;
    out[pix*3 + 0] = cr;
    out[pix*3 + 1] = cg;
    out[pix*3 + 2] = cbl;
    out[HW*3 + pix] = dep / fmaxf(acc, 1e-6f);
    out[HW*4 + pix] = (float)cnt_px;
}

extern "C" void kernel_launch(void* const* d_in, const int* in_sizes, int n_in,
                              void* d_out, int out_size, void* d_ws, size_t ws_size,
                              hipStream_t stream) {
    const float* pc    = (const float*)d_in[0];
    const float* feat  = (const float*)d_in[1];
    const int*   inval = (const int*)d_in[3];
    const float* K     = (const float*)d_in[4];
    const float* qc    = (const float*)d_in[5];
    const float* tc    = (const float*)d_in[6];
    const int*   camH  = (const int*)d_in[7];
    const int*   camW  = (const int*)d_in[8];
    const int*   band  = (const int*)d_in[9];
    float* out = (float*)d_out;

    int N = in_sizes[0] / 3;
    int side = (int)(sqrt((double)(out_size / 5)) + 0.5);
    int H = side, W = side;

    float* recs = (float*)d_ws;
    size_t keys_rounded = ((size_t)N + 3) & ~(size_t)3;
    float* keys = recs + (size_t)N * 16;
    float* sorted_recs = keys + keys_rounded;
    int*   partial = (int*)(sorted_recs + (size_t)N * 16);

    int threads = 256;
    int pblocks = (N + threads - 1) / threads;
    int nchunks = (N + 255) / 256;

    preprocess_kernel<<<pblocks, threads, 0, stream>>>(
        pc, feat, inval, K, qc, tc, camH, camW, band, recs, keys, N);
    rank_kernel<<<dim3(nchunks, nchunks), threads, 0, stream>>>(keys, partial, N);
    scatter_kernel<<<pblocks, threads, 0, stream>>>(partial, recs, sorted_recs, N, nchunks);

    int tiles = (W / TILE_SZ) * (H / TILE_SZ);
    raster_kernel<<<tiles, 256, 0, stream>>>(sorted_recs, N, camH, camW, out);
}

// Round 6
// 48.715 us; speedup vs baseline: 1.2189x; 1.2189x over previous
//
#include <hip/hip_runtime.h>
#include <math.h>

#define TILE_SZ 16
#define NEARP 0.8f
#define FARP 1000.0f
#define ATHR (1.0f/255.0f)
#define TTHR 0.0001f

// Record layout (16 floats, 64B), float4-aligned groups:
//  [0]=u    [1]=v     [2]=conic_a [3]=conic_b
//  [4]=conic_c [5]=alpha [6]=z    [7]=color_r
//  [8]=color_g [9]=color_b [10]=pad [11]=pad
//  [12]=t0x [13]=t1x  [14]=t0y    [15]=t1y     <- bounds as one float4

__global__ void preprocess_kernel(const float* __restrict__ pc,
                                  const float* __restrict__ feat,
                                  const int* __restrict__ invalid_mask,
                                  const float* __restrict__ K,
                                  const float* __restrict__ qcam,
                                  const float* __restrict__ tcam,
                                  const int* __restrict__ cam_h,
                                  const int* __restrict__ cam_w,
                                  const int* __restrict__ sh_band,
                                  float* __restrict__ recs,
                                  float* __restrict__ keys,
                                  int N)
{
    int i = blockIdx.x * blockDim.x + threadIdx.x;
    if (i >= N) return;

    float fx = K[0], cx = K[2], fy = K[4], cy = K[5];
    int H = cam_h[0], W = cam_w[0];

    float qx = qcam[0], qy = qcam[1], qz = qcam[2], qw = qcam[3];
    float qn = sqrtf(qx*qx + qy*qy + qz*qz + qw*qw);
    qx /= qn; qy /= qn; qz /= qn; qw /= qn;
    float R00 = 1.f-2.f*(qy*qy+qz*qz), R01 = 2.f*(qx*qy-qw*qz), R02 = 2.f*(qx*qz+qw*qy);
    float R10 = 2.f*(qx*qy+qw*qz), R11 = 1.f-2.f*(qx*qx+qz*qz), R12 = 2.f*(qy*qz-qw*qx);
    float R20 = 2.f*(qx*qz-qw*qy), R21 = 2.f*(qy*qz+qw*qx), R22 = 1.f-2.f*(qx*qx+qy*qy);
    float C00 = R00, C01 = R10, C02 = R20;
    float C10 = R01, C11 = R11, C12 = R21;
    float C20 = R02, C21 = R12, C22 = R22;
    float tx = tcam[0], ty = tcam[1], tz = tcam[2];
    float tcx = -(C00*tx + C01*ty + C02*tz);
    float tcy = -(C10*tx + C11*ty + C12*tz);
    float tcz = -(C20*tx + C21*ty + C22*tz);

    float px = pc[i*3+0], py = pc[i*3+1], pz = pc[i*3+2];
    float xc = C00*px + C01*py + C02*pz + tcx;
    float yc = C10*px + C11*py + C12*pz + tcy;
    float zc = C20*px + C21*py + C22*pz + tcz;
    float inv_z = 1.0f / zc;
    float u = fx * xc * inv_z + cx;
    float v = fy * yc * inv_z + cy;

    bool valid = (invalid_mask[i] == 0) && (zc > NEARP) && (zc < FARP)
              && (u > -4.0f*TILE_SZ) && (u < (float)W + 4.0f*TILE_SZ)
              && (v > -4.0f*TILE_SZ) && (v < (float)H + 4.0f*TILE_SZ);

    float q0 = feat[i*56+0], q1 = feat[i*56+1], q2 = feat[i*56+2], q3 = feat[i*56+3];
    float pn = sqrtf(q0*q0 + q1*q1 + q2*q2 + q3*q3);
    q0 /= pn; q1 /= pn; q2 /= pn; q3 /= pn;
    float P00 = 1.f-2.f*(q1*q1+q2*q2), P01 = 2.f*(q0*q1-q3*q2), P02 = 2.f*(q0*q2+q3*q1);
    float P10 = 2.f*(q0*q1+q3*q2), P11 = 1.f-2.f*(q0*q0+q2*q2), P12 = 2.f*(q1*q2-q3*q0);
    float P20 = 2.f*(q0*q2-q3*q1), P21 = 2.f*(q1*q2+q3*q0), P22 = 1.f-2.f*(q0*q0+q1*q1);
    float s0 = expf(feat[i*56+4]), s1 = expf(feat[i*56+5]), s2 = expf(feat[i*56+6]);
    float M00 = P00*s0, M01 = P01*s1, M02 = P02*s2;
    float M10 = P10*s0, M11 = P11*s1, M12 = P12*s2;
    float M20 = P20*s0, M21 = P21*s1, M22 = P22*s2;
    float S00 = M00*M00 + M01*M01 + M02*M02;
    float S01 = M00*M10 + M01*M11 + M02*M12;
    float S02 = M00*M20 + M01*M21 + M02*M22;
    float S11 = M10*M10 + M11*M11 + M12*M12;
    float S12 = M10*M20 + M11*M21 + M12*M22;
    float S22 = M20*M20 + M21*M21 + M22*M22;
    float T00 = C00*S00 + C01*S01 + C02*S02;
    float T01 = C00*S01 + C01*S11 + C02*S12;
    float T02 = C00*S02 + C01*S12 + C02*S22;
    float T10 = C10*S00 + C11*S01 + C12*S02;
    float T11 = C10*S01 + C11*S11 + C12*S12;
    float T12 = C10*S02 + C11*S12 + C12*S22;
    float T20 = C20*S00 + C21*S01 + C22*S02;
    float T21 = C20*S01 + C21*S11 + C22*S12;
    float T22 = C20*S02 + C21*S12 + C22*S22;
    float G00 = T00*C00 + T01*C01 + T02*C02;
    float G01 = T00*C10 + T01*C11 + T02*C12;
    float G02 = T00*C20 + T01*C21 + T02*C22;
    float G11 = T10*C10 + T11*C11 + T12*C12;
    float G12 = T10*C20 + T11*C21 + T12*C22;
    float G22 = T20*C20 + T21*C21 + T22*C22;
    float j00 = fx * inv_z;
    float j02 = -fx * xc * inv_z * inv_z;
    float j11 = fy * inv_z;
    float j12 = -fy * yc * inv_z * inv_z;
    float a0 = j00*G00 + j02*G02;
    float a1 = j00*G01 + j02*G12;
    float a2 = j00*G02 + j02*G22;
    float b1 = j11*G11 + j12*G12;
    float b2 = j11*G12 + j12*G22;
    float cov00 = a0*j00 + a2*j02;
    float cov01 = a1*j11 + a2*j12;
    float cov11 = b1*j11 + b2*j12;

    float A = cov00 + 0.3f;
    float B = cov01;
    float Cc = cov11 + 0.3f;
    float det = fmaxf(A*Cc - B*B, 1e-9f);
    float conic_a = Cc / det;
    float conic_b = -B / det;
    float conic_c = A / det;
    float mid = 0.5f * (A + Cc);
    float lam = mid + sqrtf(fmaxf(mid*mid - det, 1e-9f));
    float radii = ceilf(3.0f * sqrtf(lam));

    float aval = feat[i*56+7];
    float alpha = 1.0f / (1.0f + expf(-aval));

    float dnx = px - tx, dny = py - ty, dnz = pz - tz;
    float dn = sqrtf(dnx*dnx + dny*dny + dnz*dnz);
    float dx = dnx/dn, dy = dny/dn, dz = dnz/dn;
    float xx = dx*dx, yy = dy*dy, zz = dz*dz;
    float xy = dx*dy, yz = dy*dz, xz = dx*dz;
    float basis[16];
    basis[0] = 0.28209479177387814f;
    basis[1] = -0.4886025119029199f * dy;
    basis[2] = 0.4886025119029199f * dz;
    basis[3] = -0.4886025119029199f * dx;
    basis[4] = 1.0925484305920792f * xy;
    basis[5] = -1.0925484305920792f * yz;
    basis[6] = 0.31539156525252005f * (2.f*zz - xx - yy);
    basis[7] = -1.0925484305920792f * xz;
    basis[8] = 0.5462742152960396f * (xx - yy);
    basis[9] = -0.5900435899266435f * dy * (3.f*xx - yy);
    basis[10] = 2.890611442640554f * xy * dz;
    basis[11] = -0.4570457994644658f * dy * (4.f*zz - xx - yy);
    basis[12] = 0.3731763325901154f * dz * (2.f*zz - 3.f*xx - 3.f*yy);
    basis[13] = -0.4570457994644658f * dx * (4.f*zz - xx - yy);
    basis[14] = 1.445305721320277f * dz * (xx - yy);
    basis[15] = -0.5900435899266435f * dx * (xx - 3.f*yy);
    int band = sh_band[0];
    int kc = (band + 1) * (band + 1);
    float c0 = 0.f, c1 = 0.f, c2 = 0.f;
#pragma unroll
    for (int j = 0; j < 16; j++) {
        if (j < kc) {
            c0 += basis[j] * feat[i*56 + 8 + 0*16 + j];
            c1 += basis[j] * feat[i*56 + 8 + 1*16 + j];
            c2 += basis[j] * feat[i*56 + 8 + 2*16 + j];
        }
    }
    c0 = fmaxf(c0 + 0.5f, 0.0f);
    c1 = fmaxf(c1 + 0.5f, 0.0f);
    c2 = fmaxf(c2 + 0.5f, 0.0f);

    float tiles_x = (float)(W / TILE_SZ);
    float tiles_y = (float)(H / TILE_SZ);
    float t0x = fminf(fmaxf(floorf((u - radii) / TILE_SZ), 0.0f), tiles_x - 1.0f);
    float t1x = fminf(fmaxf(floorf((u + radii) / TILE_SZ), 0.0f), tiles_x - 1.0f);
    float t0y = fminf(fmaxf(floorf((v - radii) / TILE_SZ), 0.0f), tiles_y - 1.0f);
    float t1y = fminf(fmaxf(floorf((v + radii) / TILE_SZ), 0.0f), tiles_y - 1.0f);

    if (!valid) {
        t0x = 1e30f; t1x = -1e30f; t0y = 1e30f; t1y = -1e30f;
        alpha = 0.0f;
    }

    float* r = recs + (size_t)i * 16;
    r[0] = u;  r[1] = v;  r[2] = conic_a; r[3] = conic_b;
    r[4] = conic_c; r[5] = alpha; r[6] = zc; r[7] = c0;
    r[8] = c1; r[9] = c2; r[10] = 0.f; r[11] = 0.f;
    r[12] = t0x; r[13] = t1x; r[14] = t0y; r[15] = t1y;

    keys[i] = valid ? zc : INFINITY;
}

// 2D-parallel stable rank: block (ic,jc) compares 256 i's vs 256 LDS j-keys.
__global__ void rank_kernel(const float* __restrict__ keys,
                            int* __restrict__ partial,
                            int N)
{
    __shared__ float sk[256];
    int ic = blockIdx.x, jc = blockIdx.y;
    int tid = threadIdx.x;
    int i = ic * 256 + tid;
    int jbase = jc * 256;
    int m = min(256, N - jbase);
    if (tid < m) sk[tid] = keys[jbase + tid];
    __syncthreads();
    if (i >= N) return;
    float ki = keys[i];
    int r = 0;
    int m4 = m & ~3;
#pragma unroll 4
    for (int j = 0; j < m4; j += 4) {
        float4 k4 = *(const float4*)(sk + j);
        r += (k4.x < ki) || (k4.x == ki && (jbase + j    ) < i);
        r += (k4.y < ki) || (k4.y == ki && (jbase + j + 1) < i);
        r += (k4.z < ki) || (k4.z == ki && (jbase + j + 2) < i);
        r += (k4.w < ki) || (k4.w == ki && (jbase + j + 3) < i);
    }
    for (int j = m4; j < m; j++) {
        float kj = sk[j];
        r += (kj < ki) || (kj == ki && (jbase + j) < i);
    }
    partial[jc * N + i] = r;
}

__global__ void scatter_kernel(const int* __restrict__ partial,
                               const float* __restrict__ recs,
                               float* __restrict__ sorted_recs,
                               int N, int nchunks)
{
    int i = blockIdx.x * blockDim.x + threadIdx.x;
    if (i >= N) return;
    int rank = 0;
    for (int c = 0; c < nchunks; c++) rank += partial[c * N + i];
    const float4* src = (const float4*)(recs + (size_t)i * 16);
    float4* dst = (float4*)(sorted_recs + (size_t)rank * 16);
    dst[0] = src[0]; dst[1] = src[1]; dst[2] = src[2]; dst[3] = src[3];
}

// Fused per-tile raster: one block (256 threads = 4 waves) per 16x16 tile.
// Membership once per tile (2 barriers); composite phase is BARRIER-FREE:
// each wave double-buffers its own private LDS staging (load-early /
// ds_write-late) and early-exits on its own 64 pixels.
#define LIST_CAP 2048

#define COMPOSITE(P0,P1,P2) do { \
    float du = pxf - P0.x; \
    float dv = pyf - P0.y; \
    float power = -0.5f * (P0.z*du*du + P1.x*dv*dv) - P0.w*du*dv; \
    float e = __expf(power); \
    float ai = fminf(fminf(P1.y * e, P1.y), 0.99f); \
    bool eff = (ai >= ATHR) && (T > TTHR); \
    float w = eff ? T * ai : 0.0f; \
    cr  += w * P1.w; \
    cg  += w * P2.x; \
    cbl += w * P2.y; \
    dep += w * P1.z; \
    acc += w; \
    cnt_px += eff; \
    T = eff ? T * (1.0f - ai) : T; \
} while (0)

__global__ __launch_bounds__(256) void raster_kernel(
        const float* __restrict__ sorted_recs, int N,
        const int* __restrict__ cam_h,
        const int* __restrict__ cam_w,
        float* __restrict__ out)
{
    int W = cam_w[0], H = cam_h[0];
    int tiles_x = W / TILE_SZ;
    int bx = blockIdx.x % tiles_x;
    int by = blockIdx.x / tiles_x;
    int tid = threadIdx.x;
    int lane = tid & 63;
    int wv = tid >> 6;
    int px = bx * TILE_SZ + (wv & 1) * 8 + (lane & 7);
    int py = by * TILE_SZ + (wv >> 1) * 8 + (lane >> 3);
    float pxf = (float)px + 0.5f;
    float pyf = (float)py + 0.5f;
    float txf = (float)bx;
    float tyf = (float)by;

    float T = 1.0f;
    float cr = 0.f, cg = 0.f, cbl = 0.f;
    float dep = 0.f, acc = 0.f;
    int cnt_px = 0;

    __shared__ unsigned short list[LIST_CAP];   // 4KB
    __shared__ float swave[4][2][64 * 16];      // 32KB wave-private dbuf staging
    __shared__ int cntmat[32];                  // (round, wave) member counts

    for (int seg = 0; seg < N; seg += LIST_CAP) {
        if (seg) __syncthreads();               // protect list reuse across segs
        int segN = min(LIST_CAP, N - seg);
        int rounds = (segN + 255) >> 8;         // <= 8

        // ---- Phase A: batched bound loads (independent, pipelined) ----
        float4 bnd[8];
#pragma unroll
        for (int r = 0; r < 8; r++) {
            int local = (r << 8) + tid;
            if (r < rounds && local < segN) {
                bnd[r] = *(const float4*)(sorted_recs + (size_t)(seg + local) * 16 + 12);
            } else {
                bnd[r].x = 1e30f; bnd[r].y = -1e30f; bnd[r].z = 1e30f; bnd[r].w = -1e30f;
            }
        }
        unsigned pmask = 0;
#pragma unroll
        for (int r = 0; r < 8; r++) {
            bool pred = (txf >= bnd[r].x) && (txf <= bnd[r].y)
                     && (tyf >= bnd[r].z) && (tyf <= bnd[r].w);
            pmask |= ((unsigned)pred) << r;
        }
#pragma unroll
        for (int r = 0; r < 8; r++) {
            unsigned long long m = __ballot((pmask >> r) & 1u);
            if (lane == 0) cntmat[r * 4 + wv] = __popcll(m);
        }
        __syncthreads();

        // ---- Phase B: register prefix over 32 cells, then compacted writes ----
        int base[8];
        int total = 0;
#pragma unroll
        for (int k = 0; k < 32; k++) {
            if ((k & 3) == wv) base[k >> 2] = total;
            total += cntmat[k];
        }
        int cnt = total;
#pragma unroll
        for (int r = 0; r < 8; r++) {
            bool pred = (pmask >> r) & 1u;
            unsigned long long m = __ballot(pred);
            if (pred) {
                int below = __popcll(m & ((1ull << lane) - 1ull));
                list[base[r] + below] = (unsigned short)((r << 8) + tid);
            }
        }
        __syncthreads();

        // ---- Phase C: barrier-free wave-private double-buffered composite ----
        float* st0 = &swave[wv][0][0];
        float* st1 = &swave[wv][1][0];
        int r0 = lane >> 2;
        int part = lane & 3;

        // prologue: stage chunk 0 into st0 (global -> reg -> ds_write)
        if (cnt > 0) {
            float4 n0, n1, n2, n3;
            if (r0 < cnt)      n0 = ((const float4*)(sorted_recs + (size_t)(seg + (int)list[r0]) * 16))[part];
            if (16 + r0 < cnt) n1 = ((const float4*)(sorted_recs + (size_t)(seg + (int)list[16 + r0]) * 16))[part];
            if (32 + r0 < cnt) n2 = ((const float4*)(sorted_recs + (size_t)(seg + (int)list[32 + r0]) * 16))[part];
            if (48 + r0 < cnt) n3 = ((const float4*)(sorted_recs + (size_t)(seg + (int)list[48 + r0]) * 16))[part];
            if (r0 < cnt)      *(float4*)(st0 + (lane) * 4)       = n0;
            if (16 + r0 < cnt) *(float4*)(st0 + (64 + lane) * 4)  = n1;
            if (32 + r0 < cnt) *(float4*)(st0 + (128 + lane) * 4) = n2;
            if (48 + r0 < cnt) *(float4*)(st0 + (192 + lane) * 4) = n3;
        }

        bool wdead = false;
        int buf = 0;
        for (int c = 0; c < cnt && !wdead; c += 64) {
            int ecnt = min(64, cnt - c);
            float* cur = buf ? st1 : st0;
            float* oth = buf ? st0 : st1;
            int cn = c + 64;
            int rem = cnt - cn;

            // issue next-chunk global loads early (latency hides under composite)
            float4 n0, n1, n2, n3;
            if (rem > 0) {
                if (r0 < rem)      n0 = ((const float4*)(sorted_recs + (size_t)(seg + (int)list[cn + r0]) * 16))[part];
                if (16 + r0 < rem) n1 = ((const float4*)(sorted_recs + (size_t)(seg + (int)list[cn + 16 + r0]) * 16))[part];
                if (32 + r0 < rem) n2 = ((const float4*)(sorted_recs + (size_t)(seg + (int)list[cn + 32 + r0]) * 16))[part];
                if (48 + r0 < rem) n3 = ((const float4*)(sorted_recs + (size_t)(seg + (int)list[cn + 48 + r0]) * 16))[part];
            }

            // composite current chunk (broadcast LDS reads, issue-bound)
            for (int j = 0; j < ecnt; j++) {
                const float* p = cur + j * 16;
                float4 p0 = *(const float4*)p;
                float4 p1 = *(const float4*)(p + 4);
                float4 p2 = *(const float4*)(p + 8);
                COMPOSITE(p0, p1, p2);
            }
            wdead = __all(T <= TTHR);

            // write next chunk into the other buffer (same-wave lgkm ordering)
            if (rem > 0) {
                if (r0 < rem)      *(float4*)(oth + (lane) * 4)       = n0;
                if (16 + r0 < rem) *(float4*)(oth + (64 + lane) * 4)  = n1;
                if (32 + r0 < rem) *(float4*)(oth + (128 + lane) * 4) = n2;
                if (48 + r0 < rem) *(float4*)(oth + (192 + lane) * 4) = n3;
            }
            buf ^= 1;
        }
    }

    int pix = py * W + px;
    int HW = H * W;
    out[pix*3 + 0] = cr;
    out[pix*3 + 1] = cg;
    out[pix*3 + 2] = cbl;
    out[HW*3 + pix] = dep / fmaxf(acc, 1e-6f);
    out[HW*4 + pix] = (float)cnt_px;
}

extern "C" void kernel_launch(void* const* d_in, const int* in_sizes, int n_in,
                              void* d_out, int out_size, void* d_ws, size_t ws_size,
                              hipStream_t stream) {
    const float* pc    = (const float*)d_in[0];
    const float* feat  = (const float*)d_in[1];
    const int*   inval = (const int*)d_in[3];
    const float* K     = (const float*)d_in[4];
    const float* qc    = (const float*)d_in[5];
    const float* tc    = (const float*)d_in[6];
    const int*   camH  = (const int*)d_in[7];
    const int*   camW  = (const int*)d_in[8];
    const int*   band  = (const int*)d_in[9];
    float* out = (float*)d_out;

    int N = in_sizes[0] / 3;
    int side = (int)(sqrt((double)(out_size / 5)) + 0.5);
    int H = side, W = side;

    float* recs = (float*)d_ws;
    size_t keys_rounded = ((size_t)N + 3) & ~(size_t)3;
    float* keys = recs + (size_t)N * 16;
    float* sorted_recs = keys + keys_rounded;
    int*   partial = (int*)(sorted_recs + (size_t)N * 16);

    int threads = 256;
    int pblocks = (N + threads - 1) / threads;
    int nchunks = (N + 255) / 256;

    preprocess_kernel<<<pblocks, threads, 0, stream>>>(
        pc, feat, inval, K, qc, tc, camH, camW, band, recs, keys, N);
    rank_kernel<<<dim3(nchunks, nchunks), threads, 0, stream>>>(keys, partial, N);
    scatter_kernel<<<pblocks, threads, 0, stream>>>(partial, recs, sorted_recs, N, nchunks);

    int tiles = (W / TILE_SZ) * (H / TILE_SZ);
    raster_kernel<<<tiles, 256, 0, stream>>>(sorted_recs, N, camH, camW, out);
}

// Round 7
// 44.004 us; speedup vs baseline: 1.3494x; 1.1071x over previous
//
#include <hip/hip_runtime.h>
#include <math.h>

#define TILE_SZ 16
#define NEARP 0.8f
#define FARP 1000.0f
#define ATHR (1.0f/255.0f)
#define TTHR 0.0001f

// Record layout (16 floats, 64B), float4-aligned groups:
//  g0 [0:3]   = u, v, conic_a, conic_b
//  g1 [4:7]   = conic_c, alpha, z, color_r
//  g2 [8:11]  = color_g, color_b, pad, pad
//  g3 [12:15] = u, v, rmax2, packed_bounds(u8 t0x,t1x,t0y,t1y)  <- membership

__global__ void preprocess_kernel(const float* __restrict__ pc,
                                  const float* __restrict__ feat,
                                  const int* __restrict__ invalid_mask,
                                  const float* __restrict__ K,
                                  const float* __restrict__ qcam,
                                  const float* __restrict__ tcam,
                                  const int* __restrict__ cam_h,
                                  const int* __restrict__ cam_w,
                                  const int* __restrict__ sh_band,
                                  float* __restrict__ recs,
                                  float* __restrict__ keys,
                                  int N)
{
    int i = blockIdx.x * blockDim.x + threadIdx.x;
    if (i >= N) return;

    float fx = K[0], cx = K[2], fy = K[4], cy = K[5];
    int H = cam_h[0], W = cam_w[0];

    float qx = qcam[0], qy = qcam[1], qz = qcam[2], qw = qcam[3];
    float qn = sqrtf(qx*qx + qy*qy + qz*qz + qw*qw);
    qx /= qn; qy /= qn; qz /= qn; qw /= qn;
    float R00 = 1.f-2.f*(qy*qy+qz*qz), R01 = 2.f*(qx*qy-qw*qz), R02 = 2.f*(qx*qz+qw*qy);
    float R10 = 2.f*(qx*qy+qw*qz), R11 = 1.f-2.f*(qx*qx+qz*qz), R12 = 2.f*(qy*qz-qw*qx);
    float R20 = 2.f*(qx*qz-qw*qy), R21 = 2.f*(qy*qz+qw*qx), R22 = 1.f-2.f*(qx*qx+qy*qy);
    float C00 = R00, C01 = R10, C02 = R20;
    float C10 = R01, C11 = R11, C12 = R21;
    float C20 = R02, C21 = R12, C22 = R22;
    float tx = tcam[0], ty = tcam[1], tz = tcam[2];
    float tcx = -(C00*tx + C01*ty + C02*tz);
    float tcy = -(C10*tx + C11*ty + C12*tz);
    float tcz = -(C20*tx + C21*ty + C22*tz);

    float px = pc[i*3+0], py = pc[i*3+1], pz = pc[i*3+2];
    float xc = C00*px + C01*py + C02*pz + tcx;
    float yc = C10*px + C11*py + C12*pz + tcy;
    float zc = C20*px + C21*py + C22*pz + tcz;
    float inv_z = 1.0f / zc;
    float u = fx * xc * inv_z + cx;
    float v = fy * yc * inv_z + cy;

    bool valid = (invalid_mask[i] == 0) && (zc > NEARP) && (zc < FARP)
              && (u > -4.0f*TILE_SZ) && (u < (float)W + 4.0f*TILE_SZ)
              && (v > -4.0f*TILE_SZ) && (v < (float)H + 4.0f*TILE_SZ);

    float q0 = feat[i*56+0], q1 = feat[i*56+1], q2 = feat[i*56+2], q3 = feat[i*56+3];
    float pn = sqrtf(q0*q0 + q1*q1 + q2*q2 + q3*q3);
    q0 /= pn; q1 /= pn; q2 /= pn; q3 /= pn;
    float P00 = 1.f-2.f*(q1*q1+q2*q2), P01 = 2.f*(q0*q1-q3*q2), P02 = 2.f*(q0*q2+q3*q1);
    float P10 = 2.f*(q0*q1+q3*q2), P11 = 1.f-2.f*(q0*q0+q2*q2), P12 = 2.f*(q1*q2-q3*q0);
    float P20 = 2.f*(q0*q2-q3*q1), P21 = 2.f*(q1*q2+q3*q0), P22 = 1.f-2.f*(q0*q0+q1*q1);
    float s0 = expf(feat[i*56+4]), s1 = expf(feat[i*56+5]), s2 = expf(feat[i*56+6]);
    float M00 = P00*s0, M01 = P01*s1, M02 = P02*s2;
    float M10 = P10*s0, M11 = P11*s1, M12 = P12*s2;
    float M20 = P20*s0, M21 = P21*s1, M22 = P22*s2;
    float S00 = M00*M00 + M01*M01 + M02*M02;
    float S01 = M00*M10 + M01*M11 + M02*M12;
    float S02 = M00*M20 + M01*M21 + M02*M22;
    float S11 = M10*M10 + M11*M11 + M12*M12;
    float S12 = M10*M20 + M11*M21 + M12*M22;
    float S22 = M20*M20 + M21*M21 + M22*M22;
    float T00 = C00*S00 + C01*S01 + C02*S02;
    float T01 = C00*S01 + C01*S11 + C02*S12;
    float T02 = C00*S02 + C01*S12 + C02*S22;
    float T10 = C10*S00 + C11*S01 + C12*S02;
    float T11 = C10*S01 + C11*S11 + C12*S12;
    float T12 = C10*S02 + C11*S12 + C12*S22;
    float T20 = C20*S00 + C21*S01 + C22*S02;
    float T21 = C20*S01 + C21*S11 + C22*S12;
    float T22 = C20*S02 + C21*S12 + C22*S22;
    float G00 = T00*C00 + T01*C01 + T02*C02;
    float G01 = T00*C10 + T01*C11 + T02*C12;
    float G02 = T00*C20 + T01*C21 + T02*C22;
    float G11 = T10*C10 + T11*C11 + T12*C12;
    float G12 = T10*C20 + T11*C21 + T12*C22;
    float G22 = T20*C20 + T21*C21 + T22*C22;
    float j00 = fx * inv_z;
    float j02 = -fx * xc * inv_z * inv_z;
    float j11 = fy * inv_z;
    float j12 = -fy * yc * inv_z * inv_z;
    float a0 = j00*G00 + j02*G02;
    float a1 = j00*G01 + j02*G12;
    float a2 = j00*G02 + j02*G22;
    float b1 = j11*G11 + j12*G12;
    float b2 = j11*G12 + j12*G22;
    float cov00 = a0*j00 + a2*j02;
    float cov01 = a1*j11 + a2*j12;
    float cov11 = b1*j11 + b2*j12;

    float A = cov00 + 0.3f;
    float B = cov01;
    float Cc = cov11 + 0.3f;
    float det = fmaxf(A*Cc - B*B, 1e-9f);
    float conic_a = Cc / det;
    float conic_b = -B / det;
    float conic_c = A / det;
    float mid = 0.5f * (A + Cc);
    float lam = mid + sqrtf(fmaxf(mid*mid - det, 1e-9f));
    float radii = ceilf(3.0f * sqrtf(lam));

    float aval = feat[i*56+7];
    float alpha = 1.0f / (1.0f + expf(-aval));

    float dnx = px - tx, dny = py - ty, dnz = pz - tz;
    float dn = sqrtf(dnx*dnx + dny*dny + dnz*dnz);
    float dx = dnx/dn, dy = dny/dn, dz = dnz/dn;
    float xx = dx*dx, yy = dy*dy, zz = dz*dz;
    float xy = dx*dy, yz = dy*dz, xz = dx*dz;
    float basis[16];
    basis[0] = 0.28209479177387814f;
    basis[1] = -0.4886025119029199f * dy;
    basis[2] = 0.4886025119029199f * dz;
    basis[3] = -0.4886025119029199f * dx;
    basis[4] = 1.0925484305920792f * xy;
    basis[5] = -1.0925484305920792f * yz;
    basis[6] = 0.31539156525252005f * (2.f*zz - xx - yy);
    basis[7] = -1.0925484305920792f * xz;
    basis[8] = 0.5462742152960396f * (xx - yy);
    basis[9] = -0.5900435899266435f * dy * (3.f*xx - yy);
    basis[10] = 2.890611442640554f * xy * dz;
    basis[11] = -0.4570457994644658f * dy * (4.f*zz - xx - yy);
    basis[12] = 0.3731763325901154f * dz * (2.f*zz - 3.f*xx - 3.f*yy);
    basis[13] = -0.4570457994644658f * dx * (4.f*zz - xx - yy);
    basis[14] = 1.445305721320277f * dz * (xx - yy);
    basis[15] = -0.5900435899266435f * dx * (xx - 3.f*yy);
    int band = sh_band[0];
    int kc = (band + 1) * (band + 1);
    float c0 = 0.f, c1 = 0.f, c2 = 0.f;
#pragma unroll
    for (int j = 0; j < 16; j++) {
        if (j < kc) {
            c0 += basis[j] * feat[i*56 + 8 + 0*16 + j];
            c1 += basis[j] * feat[i*56 + 8 + 1*16 + j];
            c2 += basis[j] * feat[i*56 + 8 + 2*16 + j];
        }
    }
    c0 = fmaxf(c0 + 0.5f, 0.0f);
    c1 = fmaxf(c1 + 0.5f, 0.0f);
    c2 = fmaxf(c2 + 0.5f, 0.0f);

    float tiles_x = (float)(W / TILE_SZ);
    float tiles_y = (float)(H / TILE_SZ);
    float t0x = fminf(fmaxf(floorf((u - radii) / TILE_SZ), 0.0f), tiles_x - 1.0f);
    float t1x = fminf(fmaxf(floorf((u + radii) / TILE_SZ), 0.0f), tiles_x - 1.0f);
    float t0y = fminf(fmaxf(floorf((v - radii) / TILE_SZ), 0.0f), tiles_y - 1.0f);
    float t1y = fminf(fmaxf(floorf((v + radii) / TILE_SZ), 0.0f), tiles_y - 1.0f);

    // conservative reach: ai <= alpha*exp(-0.5*r^2/lam); cull iff r^2 > rmax2
    unsigned pb;
    float rmax2;
    if (valid) {
        pb = (unsigned)(int)t0x | ((unsigned)(int)t1x << 8)
           | ((unsigned)(int)t0y << 16) | ((unsigned)(int)t1y << 24);
        rmax2 = 2.0f * lam * logf(255.0f * alpha);
        if (!(rmax2 >= 0.0f)) rmax2 = -1.0f;           // alpha < 1/255, NaN-safe
        else rmax2 = rmax2 * 1.0005f + 1e-3f;          // fudge toward inclusion
    } else {
        pb = 0x00FF00FFu;                               // impossible box
        rmax2 = -1.0f;
        alpha = 0.0f;
    }

    float* r = recs + (size_t)i * 16;
    r[0] = u;  r[1] = v;  r[2] = conic_a; r[3] = conic_b;
    r[4] = conic_c; r[5] = alpha; r[6] = zc; r[7] = c0;
    r[8] = c1; r[9] = c2; r[10] = 0.f; r[11] = 0.f;
    r[12] = u; r[13] = v; r[14] = rmax2; r[15] = __uint_as_float(pb);

    keys[i] = valid ? zc : INFINITY;
}

// 2D-parallel stable rank: block (ic,jc) compares 256 i's vs 256 LDS j-keys.
__global__ void rank_kernel(const float* __restrict__ keys,
                            int* __restrict__ partial,
                            int N)
{
    __shared__ float sk[256];
    int ic = blockIdx.x, jc = blockIdx.y;
    int tid = threadIdx.x;
    int i = ic * 256 + tid;
    int jbase = jc * 256;
    int m = min(256, N - jbase);
    if (tid < m) sk[tid] = keys[jbase + tid];
    __syncthreads();
    if (i >= N) return;
    float ki = keys[i];
    int r = 0;
    int m4 = m & ~3;
#pragma unroll 4
    for (int j = 0; j < m4; j += 4) {
        float4 k4 = *(const float4*)(sk + j);
        r += (k4.x < ki) || (k4.x == ki && (jbase + j    ) < i);
        r += (k4.y < ki) || (k4.y == ki && (jbase + j + 1) < i);
        r += (k4.z < ki) || (k4.z == ki && (jbase + j + 2) < i);
        r += (k4.w < ki) || (k4.w == ki && (jbase + j + 3) < i);
    }
    for (int j = m4; j < m; j++) {
        float kj = sk[j];
        r += (kj < ki) || (kj == ki && (jbase + j) < i);
    }
    partial[jc * N + i] = r;
}

__global__ void scatter_kernel(const int* __restrict__ partial,
                               const float* __restrict__ recs,
                               float* __restrict__ sorted_recs,
                               int N, int nchunks)
{
    int i = blockIdx.x * blockDim.x + threadIdx.x;
    if (i >= N) return;
    int rank = 0;
    for (int c = 0; c < nchunks; c++) rank += partial[c * N + i];
    const float4* src = (const float4*)(recs + (size_t)i * 16);
    float4* dst = (float4*)(sorted_recs + (size_t)rank * 16);
    dst[0] = src[0]; dst[1] = src[1]; dst[2] = src[2]; dst[3] = src[3];
}

// Fused per-tile raster: one block (256 threads = 4 waves) per 16x16 tile.
// ZERO barriers: each wave builds its own per-quadrant culled list
// (tile-box AND conservative circle test) and composites with wave-private
// double-buffered LDS staging (load-early / ds_write-late).
#define LIST_CAP 2048

#define COMPOSITE(P0,P1,P2) do { \
    float du = pxf - P0.x; \
    float dv = pyf - P0.y; \
    float power = -0.5f * (P0.z*du*du + P1.x*dv*dv) - P0.w*du*dv; \
    float e = __expf(power); \
    float ai = fminf(fminf(P1.y * e, P1.y), 0.99f); \
    bool eff = (ai >= ATHR) && (T > TTHR); \
    float w = eff ? T * ai : 0.0f; \
    cr  += w * P1.w; \
    cg  += w * P2.x; \
    cbl += w * P2.y; \
    dep += w * P1.z; \
    acc += w; \
    cnt_px += eff; \
    T = eff ? T * (1.0f - ai) : T; \
} while (0)

__global__ __launch_bounds__(256) void raster_kernel(
        const float* __restrict__ sorted_recs, int N,
        const int* __restrict__ cam_h,
        const int* __restrict__ cam_w,
        float* __restrict__ out)
{
    int W = cam_w[0], H = cam_h[0];
    int tiles_x = W / TILE_SZ;
    int bx = blockIdx.x % tiles_x;
    int by = blockIdx.x / tiles_x;
    int tid = threadIdx.x;
    int lane = tid & 63;
    int wv = tid >> 6;
    int qpx0 = bx * TILE_SZ + (wv & 1) * 8;
    int qpy0 = by * TILE_SZ + (wv >> 1) * 8;
    int px = qpx0 + (lane & 7);
    int py = qpy0 + (lane >> 3);
    float pxf = (float)px + 0.5f;
    float pyf = (float)py + 0.5f;
    // quadrant pixel-center hull for the circle cull
    float qx0 = (float)qpx0 + 0.5f, qx1 = (float)qpx0 + 7.5f;
    float qy0 = (float)qpy0 + 0.5f, qy1 = (float)qpy0 + 7.5f;

    float T = 1.0f;
    float cr = 0.f, cg = 0.f, cbl = 0.f;
    float dep = 0.f, acc = 0.f;
    int cnt_px = 0;

    __shared__ unsigned short wlist[4][LIST_CAP];  // 16KB wave-private lists
    __shared__ float swave[4][2][64 * 16];         // 32KB wave-private dbuf

    unsigned short* wl = wlist[wv];
    bool wave_done = false;

    for (int seg = 0; seg < N && !wave_done; seg += LIST_CAP) {
        int segN = min(LIST_CAP, N - seg);

        // ---- membership: per-quadrant cull, wave-local compaction ----
        int cnt = 0;
        for (int base = 0; base < segN; base += 512) {   // 8 rounds per batch
            float4 g[8];
#pragma unroll
            for (int r = 0; r < 8; r++) {
                int local = base + r * 64 + lane;
                if (local < segN) {
                    g[r] = *(const float4*)(sorted_recs + (size_t)(seg + local) * 16 + 12);
                } else {
                    g[r].x = 0.f; g[r].y = 0.f; g[r].z = -1.f;
                    g[r].w = __uint_as_float(0x00FF00FFu);
                }
            }
#pragma unroll
            for (int r = 0; r < 8; r++) {
                unsigned ub = __float_as_uint(g[r].w);
                int b0x = (int)(ub & 0xFFu);
                int b1x = (int)((ub >> 8) & 0xFFu);
                int b0y = (int)((ub >> 16) & 0xFFu);
                int b1y = (int)((ub >> 24) & 0xFFu);
                bool inbox = (bx >= b0x) && (bx <= b1x) && (by >= b0y) && (by <= b1y);
                float dxc = g[r].x - fminf(fmaxf(g[r].x, qx0), qx1);
                float dyc = g[r].y - fminf(fmaxf(g[r].y, qy0), qy1);
                float r2 = dxc*dxc + dyc*dyc;
                bool pred = inbox && (r2 <= g[r].z);
                unsigned long long mm = __ballot(pred);
                if (pred) {
                    int below = __popcll(mm & ((1ull << lane) - 1ull));
                    wl[cnt + below] = (unsigned short)(base + r * 64 + lane);
                }
                cnt += __popcll(mm);
            }
        }

        // ---- barrier-free wave-private double-buffered composite ----
        float* st0 = &swave[wv][0][0];
        float* st1 = &swave[wv][1][0];
        int r0 = lane >> 2;
        int part = lane & 3;

        if (cnt > 0) {
            float4 n0, n1, n2, n3;
            if (r0 < cnt)      n0 = ((const float4*)(sorted_recs + (size_t)(seg + (int)wl[r0]) * 16))[part];
            if (16 + r0 < cnt) n1 = ((const float4*)(sorted_recs + (size_t)(seg + (int)wl[16 + r0]) * 16))[part];
            if (32 + r0 < cnt) n2 = ((const float4*)(sorted_recs + (size_t)(seg + (int)wl[32 + r0]) * 16))[part];
            if (48 + r0 < cnt) n3 = ((const float4*)(sorted_recs + (size_t)(seg + (int)wl[48 + r0]) * 16))[part];
            if (r0 < cnt)      *(float4*)(st0 + (lane) * 4)       = n0;
            if (16 + r0 < cnt) *(float4*)(st0 + (64 + lane) * 4)  = n1;
            if (32 + r0 < cnt) *(float4*)(st0 + (128 + lane) * 4) = n2;
            if (48 + r0 < cnt) *(float4*)(st0 + (192 + lane) * 4) = n3;
        }

        bool wdead = false;
        int buf = 0;
        for (int c = 0; c < cnt && !wdead; c += 64) {
            int ecnt = min(64, cnt - c);
            float* cur = buf ? st1 : st0;
            float* oth = buf ? st0 : st1;
            int cn = c + 64;
            int rem = cnt - cn;

            // issue next-chunk global loads early (latency hides under composite)
            float4 n0, n1, n2, n3;
            if (rem > 0) {
                if (r0 < rem)      n0 = ((const float4*)(sorted_recs + (size_t)(seg + (int)wl[cn + r0]) * 16))[part];
                if (16 + r0 < rem) n1 = ((const float4*)(sorted_recs + (size_t)(seg + (int)wl[cn + 16 + r0]) * 16))[part];
                if (32 + r0 < rem) n2 = ((const float4*)(sorted_recs + (size_t)(seg + (int)wl[cn + 32 + r0]) * 16))[part];
                if (48 + r0 < rem) n3 = ((const float4*)(sorted_recs + (size_t)(seg + (int)wl[cn + 48 + r0]) * 16))[part];
            }

            for (int j = 0; j < ecnt; j++) {
                const float* p = cur + j * 16;
                float4 p0 = *(const float4*)p;
                float4 p1 = *(const float4*)(p + 4);
                float4 p2 = *(const float4*)(p + 8);
                COMPOSITE(p0, p1, p2);
            }
            wdead = __all(T <= TTHR);

            if (rem > 0) {
                if (r0 < rem)      *(float4*)(oth + (lane) * 4)       = n0;
                if (16 + r0 < rem) *(float4*)(oth + (64 + lane) * 4)  = n1;
                if (32 + r0 < rem) *(float4*)(oth + (128 + lane) * 4) = n2;
                if (48 + r0 < rem) *(float4*)(oth + (192 + lane) * 4) = n3;
            }
            buf ^= 1;
        }
        wave_done = wdead;
    }

    int pix = py * W + px;
    int HW = H * W;
    out[pix*3 + 0] = cr;
    out[pix*3 + 1] = cg;
    out[pix*3 + 2] = cbl;
    out[HW*3 + pix] = dep / fmaxf(acc, 1e-6f);
    out[HW*4 + pix] = (float)cnt_px;
}

extern "C" void kernel_launch(void* const* d_in, const int* in_sizes, int n_in,
                              void* d_out, int out_size, void* d_ws, size_t ws_size,
                              hipStream_t stream) {
    const float* pc    = (const float*)d_in[0];
    const float* feat  = (const float*)d_in[1];
    const int*   inval = (const int*)d_in[3];
    const float* K     = (const float*)d_in[4];
    const float* qc    = (const float*)d_in[5];
    const float* tc    = (const float*)d_in[6];
    const int*   camH  = (const int*)d_in[7];
    const int*   camW  = (const int*)d_in[8];
    const int*   band  = (const int*)d_in[9];
    float* out = (float*)d_out;

    int N = in_sizes[0] / 3;
    int side = (int)(sqrt((double)(out_size / 5)) + 0.5);
    int H = side, W = side;

    float* recs = (float*)d_ws;
    size_t keys_rounded = ((size_t)N + 3) & ~(size_t)3;
    float* keys = recs + (size_t)N * 16;
    float* sorted_recs = keys + keys_rounded;
    int*   partial = (int*)(sorted_recs + (size_t)N * 16);

    int threads = 256;
    int pblocks = (N + threads - 1) / threads;
    int nchunks = (N + 255) / 256;

    preprocess_kernel<<<pblocks, threads, 0, stream>>>(
        pc, feat, inval, K, qc, tc, camH, camW, band, recs, keys, N);
    rank_kernel<<<dim3(nchunks, nchunks), threads, 0, stream>>>(keys, partial, N);
    scatter_kernel<<<pblocks, threads, 0, stream>>>(partial, recs, sorted_recs, N, nchunks);

    int tiles = (W / TILE_SZ) * (H / TILE_SZ);
    raster_kernel<<<tiles, 256, 0, stream>>>(sorted_recs, N, camH, camW, out);
}